// Round 1
// baseline (124.905 us; speedup 1.0000x reference)
//
#include <hip/hip_runtime.h>
#include <math.h>

#define NE 16
#define DD 256
#define NO 128
#define NIONS 4

#define NB 8            // batch elements per block
#define KT 32           // k tile
#define KSTR 20         // sS k-stride (floats), padded
#define BSTR (KT*KSTR + 4)   // 644 floats per batch in sS, padded
#define ORW 132         // orbital row stride (floats), padded
#define UNI_F (NB*16*ORW)    // 16896 floats: union of {staging, orbitals}
#define WOFF (NB*BSTR)       // 5152: W tile offset inside union

__global__ __launch_bounds__(256, 2)
void fermi_fused(const float* __restrict__ stream1e, const float* __restrict__ r_ei,
                 const float* __restrict__ Wu, const float* __restrict__ bu,
                 const float* __restrict__ piu, const float* __restrict__ au,
                 const float* __restrict__ Wd, const float* __restrict__ bd,
                 const float* __restrict__ pid_, const float* __restrict__ ad,
                 float* __restrict__ out)
{
    __shared__ __align__(16) float uni[UNI_F];          // 67.6 KB
    __shared__ float distL[NB*NE*NIONS];                // 2 KB
    __shared__ float lgL[NB*32];
    __shared__ float sgL[NB*32];

    const int t  = threadIdx.x;
    const int b0 = blockIdx.x * NB;

    // ---- electron-ion distances ----
    for (int v = t; v < NB*NE*NIONS; v += 256) {
        const int b = v >> 6, rem = v & 63, e = rem >> 2, ion = rem & 3;
        const float* rp = r_ei + (((size_t)(b0+b)*NE + e)*NIONS + ion)*3;
        const float x = rp[0], y = rp[1], z = rp[2];
        distL[v] = sqrtf(x*x + y*y + z*z);
    }

    // ---- GEMM: thread owns (batch myb, spin sp, cols jb..jb+7) x 8 electrons ----
    const int lane16 = t & 15;
    const int grp    = t >> 4;
    const int myb    = grp >> 1;    // 0..7
    const int sp     = grp & 1;
    const int jb     = lane16 * 8;

    float acc[8][8];
    #pragma unroll
    for (int i = 0; i < 8; ++i)
        #pragma unroll
        for (int j = 0; j < 8; ++j) acc[i][j] = 0.f;

    float* sS = uni;
    float* wT = uni + WOFF;

    for (int k0 = 0; k0 < DD; k0 += KT) {
        __syncthreads();
        // stage W tile (both spins): 2*KT*128 floats = 2048 float4
        #pragma unroll
        for (int rr = 0; rr < 8; ++rr) {
            const int idx = t + 256*rr;
            const int spn = idx >> 10;
            const int rem = idx & 1023;
            const int kk  = rem >> 5;
            const int c4  = rem & 31;
            const float* src = (spn ? Wd : Wu) + (size_t)(k0+kk)*NO + c4*4;
            *(float4*)(wT + spn*(KT*NO) + kk*NO + c4*4) = *(const float4*)src;
        }
        // stage s tile transposed: sS[b][k][e] = stream[b0+b][e][k0+k]
        #pragma unroll
        for (int rr = 0; rr < 4; ++rr) {
            const int idx = t + 256*rr;
            const int b   = idx >> 7;
            const int rem = idx & 127;
            const int e   = rem >> 3;
            const int kc  = rem & 7;
            const float4 v = *(const float4*)(stream1e + ((size_t)(b0+b)*NE + e)*DD + k0 + kc*4);
            float* dst = sS + b*BSTR + (kc*4)*KSTR + e;
            dst[0] = v.x; dst[KSTR] = v.y; dst[2*KSTR] = v.z; dst[3*KSTR] = v.w;
        }
        __syncthreads();

        const float* sB = sS + myb*BSTR + sp*8;
        const float* wB = wT + sp*(KT*NO) + jb;
        #pragma unroll 4
        for (int kk = 0; kk < KT; ++kk) {
            float sv[8], wv[8];
            *(float4*)&sv[0] = *(const float4*)(sB + kk*KSTR);
            *(float4*)&sv[4] = *(const float4*)(sB + kk*KSTR + 4);
            *(float4*)&wv[0] = *(const float4*)(wB + kk*NO);
            *(float4*)&wv[4] = *(const float4*)(wB + kk*NO + 4);
            #pragma unroll
            for (int i = 0; i < 8; ++i)
                #pragma unroll
                for (int j = 0; j < 8; ++j)
                    acc[i][j] = fmaf(sv[i], wv[j], acc[i][j]);
        }
    }

    // ---- envelope + bias, write orbitals to LDS (aliases staging) ----
    __syncthreads();
    {
        const float* bsp = sp ? bd   : bu;
        const float* psp = sp ? pid_ : piu;
        const float* asp = sp ? ad   : au;
        float bias[8];
        *(float4*)&bias[0] = *(const float4*)(bsp + jb);
        *(float4*)&bias[4] = *(const float4*)(bsp + jb + 4);
        #pragma unroll
        for (int i = 0; i < 8; ++i) {
            const int eg = sp*8 + i;
            float env[8];
            #pragma unroll
            for (int j = 0; j < 8; ++j) env[j] = 0.f;
            #pragma unroll
            for (int ion = 0; ion < NIONS; ++ion) {
                const float dv = distL[(myb*NE + eg)*NIONS + ion];
                float pv[8], av[8];
                *(float4*)&pv[0] = *(const float4*)(psp + ion*NO + jb);
                *(float4*)&pv[4] = *(const float4*)(psp + ion*NO + jb + 4);
                *(float4*)&av[0] = *(const float4*)(asp + ion*NO + jb);
                *(float4*)&av[4] = *(const float4*)(asp + ion*NO + jb + 4);
                #pragma unroll
                for (int j = 0; j < 8; ++j) env[j] += pv[j]*__expf(-av[j]*dv);
            }
            float o[8];
            #pragma unroll
            for (int j = 0; j < 8; ++j) o[j] = (acc[i][j] + bias[j])*env[j];
            float* dst = uni + ((size_t)myb*NE + eg)*ORW + jb;
            *(float4*)dst     = *(float4*)&o[0];
            *(float4*)(dst+4) = *(float4*)&o[4];
        }
    }
    __syncthreads();

    // ---- 8x8 slogdet: 8-lane group per determinant, loop over 8 batches ----
    {
        const int r     = t & 7;        // row held by this lane
        const int g     = t >> 3;       // det group 0..31
        const int dsp   = g >> 4;       // spin
        const int ddt   = g & 15;       // det index
        const int laneW = t & 63;
        const int gb    = laneW & ~7;   // group base lane in wave

        for (int bl = 0; bl < NB; ++bl) {
            float M[8];
            const float* mr = uni + ((size_t)bl*NE + dsp*8 + r)*ORW + ddt*8;
            *(float4*)&M[0] = *(const float4*)mr;
            *(float4*)&M[4] = *(const float4*)(mr + 4);
            float lcl = 0.f;
            int nneg = 0, step = 0, done = 0;
            #pragma unroll
            for (int c = 0; c < 8; ++c) {
                float val = done ? -1.f : fabsf(M[c]);
                float bv = val; int bl2 = r;
                #pragma unroll
                for (int off = 1; off <= 4; off <<= 1) {
                    const float ov = __shfl_xor(bv, off);
                    const int   ol = __shfl_xor(bl2, off);
                    if (ov > bv || (ov == bv && ol < bl2)) { bv = ov; bl2 = ol; }
                }
                const float pivot = __shfl(M[c], gb + bl2);
                float pr[8];
                #pragma unroll
                for (int j = 0; j < 8; ++j) pr[j] = __shfl(M[j], gb + bl2);
                if (!done) {
                    if (r == bl2) {
                        done = 1; step = c;
                        lcl += logf(fabsf(pivot));
                        nneg += (pivot < 0.f) ? 1 : 0;
                    } else {
                        const float f = (pivot != 0.f) ? (M[c]/pivot) : 0.f;
                        #pragma unroll
                        for (int j = 0; j < 8; ++j) M[j] = fmaf(-f, pr[j], M[j]);
                    }
                }
            }
            // permutation parity via inversion count of step-assignments
            int inv = 0;
            #pragma unroll
            for (int dlt = 1; dlt < 8; ++dlt) {
                const int s2 = __shfl(step, laneW + dlt);
                if (r + dlt < 8 && step > s2) inv++;
            }
            #pragma unroll
            for (int off = 1; off <= 4; off <<= 1) {
                lcl  += __shfl_xor(lcl, off);
                nneg += __shfl_xor(nneg, off);
                inv  += __shfl_xor(inv, off);
            }
            if (r == 0) {
                lgL[bl*32 + g] = lcl;
                sgL[bl*32 + g] = ((nneg + inv) & 1) ? -1.f : 1.f;
            }
        }
    }
    __syncthreads();

    // ---- signed logsumexp over 16 determinants ----
    if (t < NB) {
        float m = -INFINITY;
        float ld[16], sg[16];
        #pragma unroll
        for (int d2 = 0; d2 < 16; ++d2) {
            const float l = lgL[t*32 + d2] + lgL[t*32 + 16 + d2];
            ld[d2] = l;
            sg[d2] = sgL[t*32 + d2]*sgL[t*32 + 16 + d2];
            m = fmaxf(m, l);
        }
        float ss = 0.f;
        #pragma unroll
        for (int d2 = 0; d2 < 16; ++d2) ss += sg[d2]*__expf(ld[d2] - m);
        out[b0 + t] = m + logf(fabsf(ss));
    }
}

extern "C" void kernel_launch(void* const* d_in, const int* in_sizes, int n_in,
                              void* d_out, int out_size, void* d_ws, size_t ws_size,
                              hipStream_t stream) {
    (void)n_in; (void)d_ws; (void)ws_size;
    const float* s1e  = (const float*)d_in[0];
    const float* r_ei = (const float*)d_in[1];
    const float* Wu   = (const float*)d_in[2];
    const float* bu   = (const float*)d_in[3];
    const float* piu  = (const float*)d_in[4];
    const float* au   = (const float*)d_in[5];
    const float* Wd   = (const float*)d_in[6];
    const float* bd   = (const float*)d_in[7];
    const float* pid_ = (const float*)d_in[8];
    const float* ad   = (const float*)d_in[9];
    float* out = (float*)d_out;

    const int B = out_size;          // 4096
    dim3 grid(B / NB), block(256);
    hipLaunchKernelGGL(fermi_fused, grid, block, 0, stream,
                       s1e, r_ei, Wu, bu, piu, au, Wd, bd, pid_, ad, out);
}

// Round 2
// 68.722 us; speedup vs baseline: 1.8175x; 1.8175x over previous
//
#include <hip/hip_runtime.h>
#include <math.h>

#define NB 8             // batch elements per block
#define KT 32            // k tile (= one MFMA K)
#define DD 256
#define NO 128
#define WT_PLANE 65536   // 2*128*256 ushorts per (hi|lo) plane

typedef __attribute__((ext_vector_type(8))) short bf16x8;
typedef __attribute__((ext_vector_type(4))) float f32x4;

static __device__ inline unsigned short f2bf(float x) {
    unsigned int u = __float_as_uint(x);
    unsigned int r = (u + 0x7FFFu + ((u >> 16) & 1u)) >> 16;   // RN-even
    return (unsigned short)r;
}
static __device__ inline float bf2f(unsigned short h) {
    return __uint_as_float(((unsigned int)h) << 16);
}

// ---- pre-kernel: W (k-major) -> W^T (n-major, k contiguous), split bf16 hi/lo ----
// wt ushort layout: [hi|lo plane][spin][n(128)][k(256)]
__global__ void prep_wt(const float* __restrict__ Wu, const float* __restrict__ Wd,
                        unsigned short* __restrict__ wt) {
    const int n    = blockIdx.x & 127;
    const int spin = blockIdx.x >> 7;
    const float* W = spin ? Wd : Wu;
    const int t = threadIdx.x;          // 64
    for (int kk = t; kk < DD; kk += 64) {
        const float x = W[(size_t)kk * NO + n];
        const unsigned short h = f2bf(x);
        const unsigned short l = f2bf(x - bf2f(h));
        const size_t o = ((size_t)spin * NO + n) * DD + kk;
        wt[o]            = h;
        wt[WT_PLANE + o] = l;
    }
}

__global__ __launch_bounds__(256, 2)
void fermi_mfma(const float* __restrict__ stream1e, const float* __restrict__ r_ei,
                const float* __restrict__ bu, const float* __restrict__ piu,
                const float* __restrict__ au, const float* __restrict__ bd,
                const float* __restrict__ pid_, const float* __restrict__ ad,
                const unsigned short* __restrict__ wt,
                float* __restrict__ out)
{
    __shared__ __align__(16) float orb[128 * 128];   // 64KB; aliases bf16 staging
    __shared__ float envP[2 * 4 * NO];                // pi  [spin][ion][C]
    __shared__ float envA[2 * 4 * NO];                // a
    __shared__ float biasL[2 * NO];
    __shared__ float distL[NB * 16 * 4];
    __shared__ float lgL[NB * 32];
    __shared__ float sgL[NB * 32];

    unsigned short* A_hi = (unsigned short*)orb;      // [128][32]
    unsigned short* A_lo = A_hi + 4096;
    unsigned short* B_hi = A_hi + 8192;               // [2][128n][32k]
    unsigned short* B_lo = A_hi + 16384;

    const int t  = threadIdx.x;
    const int b0 = blockIdx.x * NB;

    // ---- stage dist, pi, a, bias (separate LDS, no alias with staging) ----
    for (int v = t; v < NB * 16 * 4; v += 256) {
        const int b = v >> 6, rem = v & 63, ge = rem >> 2, ion = rem & 3;
        const float* rp = r_ei + (((size_t)(b0 + b) * 16 + ge) * 4 + ion) * 3;
        const float x = rp[0], y = rp[1], z = rp[2];
        distL[v] = sqrtf(x * x + y * y + z * z);
    }
    for (int v = t; v < 1024; v += 256) {
        const int spin = v >> 9, rest = v & 511;
        envP[v] = (spin ? pid_ : piu)[rest];
        envA[v] = (spin ? ad   : au )[rest];
    }
    if (t < 256) {
        const int spin = t >> 7, c = t & 127;
        biasL[t] = (spin ? bd : bu)[c];
    }

    // ---- MFMA GEMM: M=128 (rows: sp*64 + b*8 + e), N=128, K=256 ----
    const int w    = t >> 6;          // wave 0..3
    const int lane = t & 63;
    const int lr   = lane & 15;
    const int lg   = lane >> 4;
    const int bsp  = w >> 1;          // spin handled by this wave

    f32x4 acc[2][8];
    #pragma unroll
    for (int mt = 0; mt < 2; ++mt)
        #pragma unroll
        for (int nt = 0; nt < 8; ++nt)
            acc[mt][nt] = (f32x4){0.f, 0.f, 0.f, 0.f};

    for (int k0 = 0; k0 < DD; k0 += KT) {
        __syncthreads();   // previous tile's frag reads complete

        // stage A: stream fp32 -> bf16 hi/lo, LDS [row][k] (k contig)
        #pragma unroll
        for (int rr = 0; rr < 4; ++rr) {
            const int idx = t + 256 * rr;         // 0..1023
            const int r = idx >> 3, k4 = idx & 7;
            const int sp_ = r >> 6, b_ = (r >> 3) & 7, e_ = r & 7;
            const float4 v = *(const float4*)(stream1e +
                ((size_t)(b0 + b_) * 16 + sp_ * 8 + e_) * DD + k0 + k4 * 4);
            ushort4 h, l;
            h.x = f2bf(v.x); l.x = f2bf(v.x - bf2f(h.x));
            h.y = f2bf(v.y); l.y = f2bf(v.y - bf2f(h.y));
            h.z = f2bf(v.z); l.z = f2bf(v.z - bf2f(h.z));
            h.w = f2bf(v.w); l.w = f2bf(v.w - bf2f(h.w));
            *(ushort4*)(A_hi + r * KT + k4 * 4) = h;
            *(ushort4*)(A_lo + r * KT + k4 * 4) = l;
        }
        // stage B: pre-split W^T bf16, linear 16B copies
        #pragma unroll
        for (int rr = 0; rr < 8; ++rr) {
            const int c  = t + 256 * rr;          // 0..2047
            const int hl = c >> 10;
            const int cc = c & 1023;
            const int sn = cc >> 2, kk = (cc & 3) * 8;
            const uint4 vv = *(const uint4*)(wt + hl * WT_PLANE + sn * DD + k0 + kk);
            *(uint4*)((hl ? B_lo : B_hi) + cc * 8) = vv;
        }
        __syncthreads();

        bf16x8 ah0, ah1, al0, al1;
        {
            const unsigned short* pa = A_hi + (w * 32 + lr) * KT + lg * 8;
            ah0 = *(const bf16x8*)pa;
            ah1 = *(const bf16x8*)(pa + 16 * KT);
            const unsigned short* pl = A_lo + (w * 32 + lr) * KT + lg * 8;
            al0 = *(const bf16x8*)pl;
            al1 = *(const bf16x8*)(pl + 16 * KT);
        }
        #pragma unroll
        for (int nt = 0; nt < 8; ++nt) {
            const int nrow = bsp * NO + nt * 16 + lr;
            const bf16x8 bh  = *(const bf16x8*)(B_hi + nrow * KT + lg * 8);
            const bf16x8 bl_ = *(const bf16x8*)(B_lo + nrow * KT + lg * 8);
            acc[0][nt] = __builtin_amdgcn_mfma_f32_16x16x32_bf16(ah0, bh,  acc[0][nt], 0, 0, 0);
            acc[0][nt] = __builtin_amdgcn_mfma_f32_16x16x32_bf16(ah0, bl_, acc[0][nt], 0, 0, 0);
            acc[0][nt] = __builtin_amdgcn_mfma_f32_16x16x32_bf16(al0, bh,  acc[0][nt], 0, 0, 0);
            acc[1][nt] = __builtin_amdgcn_mfma_f32_16x16x32_bf16(ah1, bh,  acc[1][nt], 0, 0, 0);
            acc[1][nt] = __builtin_amdgcn_mfma_f32_16x16x32_bf16(ah1, bl_, acc[1][nt], 0, 0, 0);
            acc[1][nt] = __builtin_amdgcn_mfma_f32_16x16x32_bf16(al1, bh,  acc[1][nt], 0, 0, 0);
        }
    }

    __syncthreads();   // all frag reads done before orb overwrites staging

    // ---- epilogue: bias + envelope, write orbitals fp32 to LDS ----
    {
        const float* eP = envP + bsp * 512;
        const float* eA = envA + bsp * 512;
        const float* bi = biasL + bsp * NO;
        #pragma unroll
        for (int mt = 0; mt < 2; ++mt) {
            #pragma unroll
            for (int q = 0; q < 4; ++q) {
                const int R  = w * 32 + mt * 16 + lg * 4 + q;
                const int b_ = (R >> 3) & 7;
                const int ge = bsp * 8 + (R & 7);
                const float d0 = distL[(b_ * 16 + ge) * 4 + 0];
                const float d1 = distL[(b_ * 16 + ge) * 4 + 1];
                const float d2 = distL[(b_ * 16 + ge) * 4 + 2];
                const float d3 = distL[(b_ * 16 + ge) * 4 + 3];
                #pragma unroll
                for (int nt = 0; nt < 8; ++nt) {
                    const int C = nt * 16 + lr;
                    const float env = eP[C]       * __expf(-eA[C]       * d0)
                                    + eP[128 + C] * __expf(-eA[128 + C] * d1)
                                    + eP[256 + C] * __expf(-eA[256 + C] * d2)
                                    + eP[384 + C] * __expf(-eA[384 + C] * d3);
                    orb[R * 128 + C] = (acc[mt][nt][q] + bi[C]) * env;
                }
            }
        }
    }
    __syncthreads();

    // ---- 8x8 slogdet: 8-lane group per determinant ----
    {
        const int r     = t & 7;
        const int g     = t >> 3;       // 0..31
        const int dsp   = g >> 4;
        const int ddt   = g & 15;
        const int laneW = t & 63;
        const int gb    = laneW & ~7;

        for (int blb = 0; blb < NB; ++blb) {
            float M[8];
            const float* mr = orb + ((size_t)dsp * 64 + blb * 8 + r) * 128 + ddt * 8;
            *(float4*)&M[0] = *(const float4*)mr;
            *(float4*)&M[4] = *(const float4*)(mr + 4);
            float lcl = 0.f;
            int nneg = 0, step = 0, done = 0;
            #pragma unroll
            for (int c = 0; c < 8; ++c) {
                float val = done ? -1.f : fabsf(M[c]);
                float bv = val; int bl2 = r;
                #pragma unroll
                for (int off = 1; off <= 4; off <<= 1) {
                    const float ov = __shfl_xor(bv, off);
                    const int   ol = __shfl_xor(bl2, off);
                    if (ov > bv || (ov == bv && ol < bl2)) { bv = ov; bl2 = ol; }
                }
                const float pivot = __shfl(M[c], gb + bl2);
                float pr[8];
                #pragma unroll
                for (int j = 0; j < 8; ++j) pr[j] = __shfl(M[j], gb + bl2);
                if (!done) {
                    if (r == bl2) {
                        done = 1; step = c;
                        lcl += logf(fabsf(pivot));
                        nneg += (pivot < 0.f) ? 1 : 0;
                    } else {
                        const float f = (pivot != 0.f) ? (M[c] / pivot) : 0.f;
                        #pragma unroll
                        for (int j = 0; j < 8; ++j) M[j] = fmaf(-f, pr[j], M[j]);
                    }
                }
            }
            int inv = 0;
            #pragma unroll
            for (int dlt = 1; dlt < 8; ++dlt) {
                const int s2 = __shfl(step, laneW + dlt);
                if (r + dlt < 8 && step > s2) inv++;
            }
            #pragma unroll
            for (int off = 1; off <= 4; off <<= 1) {
                lcl  += __shfl_xor(lcl, off);
                nneg += __shfl_xor(nneg, off);
                inv  += __shfl_xor(inv, off);
            }
            if (r == 0) {
                lgL[blb * 32 + g] = lcl;
                sgL[blb * 32 + g] = ((nneg + inv) & 1) ? -1.f : 1.f;
            }
        }
    }
    __syncthreads();

    // ---- signed logsumexp over 16 determinants ----
    if (t < NB) {
        float m = -INFINITY;
        float ld[16], sg[16];
        #pragma unroll
        for (int d2 = 0; d2 < 16; ++d2) {
            const float l = lgL[t * 32 + d2] + lgL[t * 32 + 16 + d2];
            ld[d2] = l;
            sg[d2] = sgL[t * 32 + d2] * sgL[t * 32 + 16 + d2];
            m = fmaxf(m, l);
        }
        float ss = 0.f;
        #pragma unroll
        for (int d2 = 0; d2 < 16; ++d2) ss += sg[d2] * __expf(ld[d2] - m);
        out[b0 + t] = m + logf(fabsf(ss));
    }
}

extern "C" void kernel_launch(void* const* d_in, const int* in_sizes, int n_in,
                              void* d_out, int out_size, void* d_ws, size_t ws_size,
                              hipStream_t stream) {
    (void)n_in; (void)in_sizes;
    const float* s1e  = (const float*)d_in[0];
    const float* r_ei = (const float*)d_in[1];
    const float* Wu   = (const float*)d_in[2];
    const float* bu   = (const float*)d_in[3];
    const float* piu  = (const float*)d_in[4];
    const float* au   = (const float*)d_in[5];
    const float* Wd   = (const float*)d_in[6];
    const float* bd   = (const float*)d_in[7];
    const float* pid_ = (const float*)d_in[8];
    const float* ad   = (const float*)d_in[9];
    float* out = (float*)d_out;
    unsigned short* wt = (unsigned short*)d_ws;   // needs 2*2*128*256*2B = 256KB
    (void)ws_size;

    // W^T + bf16 hi/lo split (256KB, L2-resident for the main kernel)
    hipLaunchKernelGGL(prep_wt, dim3(256), dim3(64), 0, stream, Wu, Wd, wt);

    const int B = out_size;   // 4096
    hipLaunchKernelGGL(fermi_mfma, dim3(B / NB), dim3(256), 0, stream,
                       s1e, r_ei, bu, piu, au, bd, pid_, ad, wt, out);
}

// Round 3
// 55.266 us; speedup vs baseline: 2.2601x; 1.2435x over previous
//
#include <hip/hip_runtime.h>
#include <math.h>

#define DD 256
#define NO 128
#define WT_PLANE 65536          // ushorts per (hi|lo) plane: 2*128*256
#define ORW 132                 // orb row stride in floats (132 ≡ 4 mod 32 → 2-way banks)
#define ORB_WAVE (32*ORW)       // floats per wave tile

typedef __attribute__((ext_vector_type(8))) short bf16x8;
typedef __attribute__((ext_vector_type(4))) float f32x4;

static __device__ inline unsigned short f2bf(float x) {
    unsigned int u = __float_as_uint(x);
    unsigned int r = (u + 0x7FFFu + ((u >> 16) & 1u)) >> 16;   // RN-even
    return (unsigned short)r;
}
static __device__ inline float bf2f(unsigned short h) {
    return __uint_as_float(((unsigned int)h) << 16);
}

// ---- pre-kernel: W (k-major) -> W^T (n-major, k contiguous), split bf16 hi/lo ----
// wt ushort layout: [hi|lo plane][spin][n(128)][k(256)]
__global__ void prep_wt(const float* __restrict__ Wu, const float* __restrict__ Wd,
                        unsigned short* __restrict__ wt) {
    const int n    = blockIdx.x & 127;
    const int spin = blockIdx.x >> 7;
    const float* W = spin ? Wd : Wu;
    const int t = threadIdx.x;          // 64
    for (int kk = t; kk < DD; kk += 64) {
        const float x = W[(size_t)kk * NO + n];
        const unsigned short h = f2bf(x);
        const unsigned short l = f2bf(x - bf2f(h));
        const size_t o = ((size_t)spin * NO + n) * DD + kk;
        wt[o]            = h;
        wt[WT_PLANE + o] = l;
    }
}

__global__ __launch_bounds__(256, 2)
void fermi_main(const float* __restrict__ stream1e, const float* __restrict__ r_ei,
                const float* __restrict__ bu, const float* __restrict__ piu,
                const float* __restrict__ au, const float* __restrict__ bd,
                const float* __restrict__ pid_, const float* __restrict__ ad,
                const unsigned short* __restrict__ wt, float* __restrict__ out)
{
    __shared__ __align__(16) float orb[4 * ORB_WAVE];   // 67.6 KB
    __shared__ __align__(16) float distL[4 * 32 * 4];   // 2 KB  [wave][row][ion]
    __shared__ float exL[2 * 8 * 16 * 2];               // 2 KB  [sp][b][det][l,s]

    const int t    = threadIdx.x;
    const int w    = t >> 6;
    const int lane = t & 63;
    const int lr   = lane & 15;
    const int lg   = lane >> 4;
    const int sp   = w >> 1;            // wave's spin
    const int bh   = w & 1;             // batch half (0: b0..3, 1: b4..7)
    const int b0   = blockIdx.x * 8;

    // ---- dists for this wave's 32 rows x 4 ions (2 entries/lane) ----
    #pragma unroll
    for (int i = 0; i < 2; ++i) {
        const int idx = lane * 2 + i;           // 0..127
        const int row = idx >> 2, ion = idx & 3;
        const int b  = b0 + bh * 4 + (row >> 3);
        const int ge = sp * 8 + (row & 7);
        const float* rp = r_ei + (((size_t)b * 16 + ge) * 4 + ion) * 3;
        const float x = rp[0], y = rp[1], z = rp[2];
        distL[(w * 32 + row) * 4 + ion] = sqrtf(x * x + y * y + z * z);
    }
    // same-wave produce/consume: no barrier needed (lgkmcnt handles ordering)

    // ---- A row bases (element offsets into stream1e) ----
    size_t arow0, arow1;
    {
        const int r0 = lr;            // mt=0 rows 0..15
        const int r1 = 16 + lr;       // mt=1 rows 16..31
        arow0 = (((size_t)(b0 + bh * 4 + (r0 >> 3)) * 16) + sp * 8 + (r0 & 7)) * DD;
        arow1 = (((size_t)(b0 + bh * 4 + (r1 >> 3)) * 16) + sp * 8 + (r1 & 7)) * DD;
    }
    const unsigned short* wts = wt + (size_t)sp * NO * DD;   // hi base for this spin

    f32x4 acc[2][8];
    #pragma unroll
    for (int mt = 0; mt < 2; ++mt)
        #pragma unroll
        for (int nt = 0; nt < 8; ++nt)
            acc[mt][nt] = (f32x4){0.f, 0.f, 0.f, 0.f};

    // ---- barrier-free MFMA GEMM over K=256 ----
    #pragma unroll
    for (int kt = 0; kt < 8; ++kt) {
        const int k0 = kt * 32;
        int ahw[2][4], alw[2][4];
        #pragma unroll
        for (int mt = 0; mt < 2; ++mt) {
            const float* ap = stream1e + (mt ? arow1 : arow0) + k0 + lg * 8;
            const float4 v0 = *(const float4*)ap;
            const float4 v1 = *(const float4*)(ap + 4);
            const float f[8] = {v0.x, v0.y, v0.z, v0.w, v1.x, v1.y, v1.z, v1.w};
            #pragma unroll
            for (int p = 0; p < 4; ++p) {
                unsigned int hp;
                asm("v_cvt_pk_bf16_f32 %0, %1, %2" : "=v"(hp) : "v"(f[2*p]), "v"(f[2*p+1]));
                const float h0 = __uint_as_float(hp << 16);
                const float h1 = __uint_as_float(hp & 0xFFFF0000u);
                const float l0 = f[2*p]   - h0;
                const float l1 = f[2*p+1] - h1;
                unsigned int lp;
                asm("v_cvt_pk_bf16_f32 %0, %1, %2" : "=v"(lp) : "v"(l0), "v"(l1));
                ahw[mt][p] = (int)hp;
                alw[mt][p] = (int)lp;
            }
        }
        const bf16x8 ah0 = *(const bf16x8*)ahw[0];
        const bf16x8 al0 = *(const bf16x8*)alw[0];
        const bf16x8 ah1 = *(const bf16x8*)ahw[1];
        const bf16x8 al1 = *(const bf16x8*)alw[1];

        #pragma unroll
        for (int nt = 0; nt < 8; ++nt) {
            const size_t off = ((size_t)(nt * 16 + lr)) * DD + k0 + lg * 8;
            const bf16x8 bh_ = *(const bf16x8*)(wts + off);
            const bf16x8 bl_ = *(const bf16x8*)(wts + WT_PLANE + off);
            acc[0][nt] = __builtin_amdgcn_mfma_f32_16x16x32_bf16(ah0, bh_, acc[0][nt], 0, 0, 0);
            acc[0][nt] = __builtin_amdgcn_mfma_f32_16x16x32_bf16(ah0, bl_, acc[0][nt], 0, 0, 0);
            acc[0][nt] = __builtin_amdgcn_mfma_f32_16x16x32_bf16(al0, bh_, acc[0][nt], 0, 0, 0);
            acc[1][nt] = __builtin_amdgcn_mfma_f32_16x16x32_bf16(ah1, bh_, acc[1][nt], 0, 0, 0);
            acc[1][nt] = __builtin_amdgcn_mfma_f32_16x16x32_bf16(ah1, bl_, acc[1][nt], 0, 0, 0);
            acc[1][nt] = __builtin_amdgcn_mfma_f32_16x16x32_bf16(al1, bh_, acc[1][nt], 0, 0, 0);
        }
    }

    // ---- epilogue: bias + envelope, write orbitals to this wave's LDS tile ----
    float dreg[2][4][4];
    #pragma unroll
    for (int mt = 0; mt < 2; ++mt)
        #pragma unroll
        for (int q = 0; q < 4; ++q) {
            const int row = mt * 16 + lg * 4 + q;
            const f32x4 dv = *(const f32x4*)&distL[(w * 32 + row) * 4];
            dreg[mt][q][0] = dv[0]; dreg[mt][q][1] = dv[1];
            dreg[mt][q][2] = dv[2]; dreg[mt][q][3] = dv[3];
        }
    {
        const float* pi_s = sp ? pid_ : piu;
        const float* a_s  = sp ? ad   : au;
        const float* b_s  = sp ? bd   : bu;
        float* ow = orb + (size_t)w * ORB_WAVE;
        #pragma unroll
        for (int nt = 0; nt < 8; ++nt) {
            const int C = nt * 16 + lr;
            float pv[4], av[4];
            #pragma unroll
            for (int ion = 0; ion < 4; ++ion) {
                pv[ion] = pi_s[ion * NO + C];
                av[ion] = a_s [ion * NO + C];
            }
            const float bias = b_s[C];
            #pragma unroll
            for (int mt = 0; mt < 2; ++mt)
                #pragma unroll
                for (int q = 0; q < 4; ++q) {
                    const int row = mt * 16 + lg * 4 + q;
                    float env = 0.f;
                    #pragma unroll
                    for (int ion = 0; ion < 4; ++ion)
                        env += pv[ion] * __expf(-av[ion] * dreg[mt][q][ion]);
                    ow[row * ORW + C] = (acc[mt][nt][q] + bias) * env;
                }
        }
    }
    // same-wave LDS RAW again: no barrier

    // ---- per-lane 8x8 slogdet (register LU, conditional-swap pivoting) ----
    {
        const int bl_ = lane >> 4;      // local batch 0..3
        const int dd  = lane & 15;      // determinant index
        const float* ow = orb + (size_t)w * ORB_WAVE;
        float M[8][8];
        #pragma unroll
        for (int e = 0; e < 8; ++e) {
            const float* pr = ow + (bl_ * 8 + e) * ORW + dd * 8;
            const f32x4 u0 = *(const f32x4*)pr;
            const f32x4 u1 = *(const f32x4*)(pr + 4);
            M[e][0] = u0[0]; M[e][1] = u0[1]; M[e][2] = u0[2]; M[e][3] = u0[3];
            M[e][4] = u1[0]; M[e][5] = u1[1]; M[e][6] = u1[2]; M[e][7] = u1[3];
        }
        float ldet = 0.f, sgn = 1.f;
        #pragma unroll
        for (int c = 0; c < 8; ++c) {
            #pragma unroll
            for (int r = c + 1; r < 8; ++r) {
                const bool swp = fabsf(M[r][c]) > fabsf(M[c][c]);
                sgn = swp ? -sgn : sgn;
                #pragma unroll
                for (int j = c; j < 8; ++j) {
                    const float x1 = M[c][j], x2 = M[r][j];
                    M[c][j] = swp ? x2 : x1;
                    M[r][j] = swp ? x1 : x2;
                }
            }
            const float p = M[c][c];
            ldet += __logf(fabsf(p));
            sgn  = (p < 0.f) ? -sgn : sgn;
            const float rp = (p != 0.f) ? (1.0f / p) : 0.f;
            #pragma unroll
            for (int r = c + 1; r < 8; ++r) {
                const float fm = M[r][c] * rp;
                #pragma unroll
                for (int j = c + 1; j < 8; ++j)
                    M[r][j] = fmaf(-fm, M[c][j], M[r][j]);
            }
        }
        const int bb = bh * 4 + bl_;    // block-local batch 0..7
        exL[((sp * 8 + bb) * 16 + dd) * 2 + 0] = ldet;
        exL[((sp * 8 + bb) * 16 + dd) * 2 + 1] = sgn;
    }
    __syncthreads();

    // ---- signed logsumexp over 16 determinants (threads 0..127) ----
    if (t < 128) {
        const int b  = t >> 4;
        const int d2 = t & 15;
        const float lu = exL[((b)     * 16 + d2) * 2 + 0];
        const float su = exL[((b)     * 16 + d2) * 2 + 1];
        const float ldn= exL[((8 + b) * 16 + d2) * 2 + 0];
        const float sdn= exL[((8 + b) * 16 + d2) * 2 + 1];
        const float l  = lu + ldn;
        const float s  = su * sdn;
        float m = l;
        #pragma unroll
        for (int off = 1; off <= 8; off <<= 1) m = fmaxf(m, __shfl_xor(m, off));
        float ss = s * __expf(l - m);
        #pragma unroll
        for (int off = 1; off <= 8; off <<= 1) ss += __shfl_xor(ss, off);
        if (d2 == 0) out[b0 + b] = m + __logf(fabsf(ss));
    }
}

extern "C" void kernel_launch(void* const* d_in, const int* in_sizes, int n_in,
                              void* d_out, int out_size, void* d_ws, size_t ws_size,
                              hipStream_t stream) {
    (void)n_in; (void)in_sizes; (void)ws_size;
    const float* s1e  = (const float*)d_in[0];
    const float* r_ei = (const float*)d_in[1];
    const float* Wu   = (const float*)d_in[2];
    const float* bu   = (const float*)d_in[3];
    const float* piu  = (const float*)d_in[4];
    const float* au   = (const float*)d_in[5];
    const float* Wd   = (const float*)d_in[6];
    const float* bd   = (const float*)d_in[7];
    const float* pid_ = (const float*)d_in[8];
    const float* ad   = (const float*)d_in[9];
    float* out = (float*)d_out;
    unsigned short* wt = (unsigned short*)d_ws;   // 256 KB

    hipLaunchKernelGGL(prep_wt, dim3(256), dim3(64), 0, stream, Wu, Wd, wt);

    const int B = out_size;   // 4096
    hipLaunchKernelGGL(fermi_main, dim3(B / 8), dim3(256), 0, stream,
                       s1e, r_ei, bu, piu, au, bd, pid_, ad, wt, out);
}